// Round 6
// baseline (56.527 us; speedup 1.0000x reference)
//
#include <hip/hip_runtime.h>
#include <math.h>

#define D_IN  2048
#define D_OUT 8192

// Two rows per 128-thread block. Wave w computes FWHT-2048 of row 2b+w
// (non-redundant), both waves then cooperate on each row's FWHT-8192.
// All cross-lane butterflies on the VALU pipe (DPP / permlane_swap); DS pipe
// only for: A-store (8xb128), random gather (64xb32/row), one cross-wave
// half-exchange per row (32xb128). Ascending-h order, exact lo+hi/lo-hi
// association throughout (matches reference fp32 rounding).
//
// DPP direction convention (GCN): row_ror:N => dst[i] = src[(i-N) mod 16].

#if __has_builtin(__builtin_amdgcn_permlane16_swap) && __has_builtin(__builtin_amdgcn_permlane32_swap)
#define HAVE_PLSWAP 1
#endif

template<int CTRL>
__device__ __forceinline__ float dpp_full(float x) {
  int xi = __float_as_int(x);
  return __int_as_float(__builtin_amdgcn_update_dpp(xi, xi, CTRL, 0xF, 0xF, true));
}
// partner across lane-xor-4: ror:4 feeds banks {1,3} (bit2=1), ror:12 feeds {0,2}
__device__ __forceinline__ float dpp_xor4(float x) {
  int xi = __float_as_int(x);
  int r = __builtin_amdgcn_update_dpp(0, xi, 0x124, 0xF, 0xA, false);  // ror:4  -> banks 1,3
  r     = __builtin_amdgcn_update_dpp(r,  xi, 0x12C, 0xF, 0x5, false); // ror:12 -> banks 0,2
  return __int_as_float(r);
}

__device__ __forceinline__ void bfly_pl16(float& A, float& B, float sgn) {
#ifdef HAVE_PLSWAP
  auto r0 = __builtin_amdgcn_permlane16_swap(__float_as_uint(A), __float_as_uint(B), false, false);
  float lo = __uint_as_float(r0[0]), hi = __uint_as_float(r0[1]);
  float s = lo + hi, d = lo - hi;
  auto r1 = __builtin_amdgcn_permlane16_swap(__float_as_uint(s), __float_as_uint(d), false, false);
  A = __uint_as_float(r1[0]); B = __uint_as_float(r1[1]);
  (void)sgn;
#else
  float pA = __shfl_xor(A, 16, 64); A = fmaf(sgn, A, pA);
  float pB = __shfl_xor(B, 16, 64); B = fmaf(sgn, B, pB);
#endif
}
__device__ __forceinline__ void bfly_pl32(float& A, float& B, float sgn) {
#ifdef HAVE_PLSWAP
  auto r0 = __builtin_amdgcn_permlane32_swap(__float_as_uint(A), __float_as_uint(B), false, false);
  float lo = __uint_as_float(r0[0]), hi = __uint_as_float(r0[1]);
  float s = lo + hi, d = lo - hi;
  auto r1 = __builtin_amdgcn_permlane32_swap(__float_as_uint(s), __float_as_uint(d), false, false);
  A = __uint_as_float(r1[0]); B = __uint_as_float(r1[1]);
  (void)sgn;
#else
  float pA = __shfl_xor(A, 32, 64); A = fmaf(sgn, A, pA);
  float pB = __shfl_xor(B, 32, 64); B = fmaf(sgn, B, pB);
#endif
}

__global__ __launch_bounds__(128, 2) void fastfood_kernel(
    const float* __restrict__ xg, const float* __restrict__ Bg,
    const float* __restrict__ Gg, const float* __restrict__ Sg,
    const int*   __restrict__ Pg, const float* __restrict__ Ug,
    float* __restrict__ outg)
{
  __shared__ float4 A4s[2][D_IN / 4];  // 2 x 8 KB: per-row FWHT-2048 results
  __shared__ float4 X4s[4096 / 4];     // 16 KB: cross-wave exchange buffer

  const int t = threadIdx.x, lane = t & 63, wave = t >> 6;
  const int row0 = 2 * blockIdx.x;
  const float sg1  = (lane & 1)  ? -1.f : 1.f;
  const float sg2  = (lane & 2)  ? -1.f : 1.f;
  const float sg4  = (lane & 4)  ? -1.f : 1.f;
  const float sg8  = (lane & 8)  ? -1.f : 1.f;
  const float sg16 = (lane & 16) ? -1.f : 1.f;
  const float sg32 = (lane & 32) ? -1.f : 1.f;

  // ===== FWHT-2048 of B*x for OWN row (wave w -> row row0+w), in registers =====
  // element d = c(bits0-1) | lane<<2 | j<<8  (j = quad 0..7)
  float a[32];
  {
    const float4* x4 = reinterpret_cast<const float4*>(xg + (size_t)(row0 + wave) * D_IN);
    const float4* B4 = reinterpret_cast<const float4*>(Bg);
#pragma unroll
    for (int j = 0; j < 8; ++j) {
      float4 xv = x4[lane + 64 * j], bv = B4[lane + 64 * j];
      a[4*j+0] = xv.x * bv.x; a[4*j+1] = xv.y * bv.y;
      a[4*j+2] = xv.z * bv.z; a[4*j+3] = xv.w * bv.w;
    }
  }
#pragma unroll
  for (int j = 0; j < 8; ++j) {                                  // h=1,2
    float x0=a[4*j],x1=a[4*j+1],x2=a[4*j+2],x3=a[4*j+3];
    float y0=x0+x1,y1=x0-x1,y2=x2+x3,y3=x2-x3;
    a[4*j]=y0+y2; a[4*j+2]=y0-y2; a[4*j+1]=y1+y3; a[4*j+3]=y1-y3;
  }
#pragma unroll
  for (int k = 0; k < 32; ++k) { float p = dpp_full<0xB1>(a[k]);  a[k] = fmaf(sg1, a[k], p); }  // h=4
#pragma unroll
  for (int k = 0; k < 32; ++k) { float p = dpp_full<0x4E>(a[k]);  a[k] = fmaf(sg2, a[k], p); }  // h=8
#pragma unroll
  for (int k = 0; k < 32; ++k) { float p = dpp_xor4(a[k]);        a[k] = fmaf(sg4, a[k], p); }  // h=16
#pragma unroll
  for (int k = 0; k < 32; ++k) { float p = dpp_full<0x128>(a[k]); a[k] = fmaf(sg8, a[k], p); }  // h=32
#pragma unroll
  for (int k = 0; k < 32; k += 2) bfly_pl16(a[k], a[k+1], sg16);                                // h=64
#pragma unroll
  for (int k = 0; k < 32; k += 2) bfly_pl32(a[k], a[k+1], sg32);                                // h=128
#pragma unroll
  for (int b = 1; b < 8; b <<= 1)                                                               // h=256..1024
#pragma unroll
    for (int j = 0; j < 8; ++j) if (!(j & b))
#pragma unroll
      for (int c = 0; c < 4; ++c) {
        float lo = a[4*j+c], hi = a[4*(j|b)+c];
        a[4*j+c] = lo + hi; a[4*(j|b)+c] = lo - hi;
      }
  // store own row's full result (8 x b128, contiguous per instr)
#pragma unroll
  for (int j = 0; j < 8; ++j)
    A4s[wave][lane + 64 * j] = make_float4(a[4*j], a[4*j+1], a[4*j+2], a[4*j+3]);

  // prefetch permutation (row-independent) while the store settles
  int4 pp[16];
  {
    const int4* P4 = reinterpret_cast<const int4*>(Pg);
#pragma unroll
    for (int q = 0; q < 16; ++q) pp[q] = P4[lane + 64 * q + 1024 * wave];
  }
  __syncthreads();   // #1

  const float c1 = (float)(1.0 / (6.283185307179586 * 90.50966799187808)); // 1/(2*pi*sqrt(8192))
  const float4* G4 = reinterpret_cast<const float4*>(Gg);
  const float4* S4 = reinterpret_cast<const float4*>(Sg);
  const float4* U4 = reinterpret_cast<const float4*>(Ug);

#pragma unroll 1
  for (int rr = 0; rr < 2; ++rr) {
    const float* a_f = reinterpret_cast<const float*>(A4s[rr]);

    // ===== gather + Gaussian scale:  o = c | lane<<2 | q<<8 | wave<<12 =====
    float v[64];
#pragma unroll
    for (int q = 0; q < 16; ++q) {
      int idx = lane + 64 * q + 1024 * wave;
      float4 gv = G4[idx];
      v[4*q+0] = a_f[pp[q].x & (D_IN-1)] * gv.x;
      v[4*q+1] = a_f[pp[q].y & (D_IN-1)] * gv.y;
      v[4*q+2] = a_f[pp[q].z & (D_IN-1)] * gv.z;
      v[4*q+3] = a_f[pp[q].w & (D_IN-1)] * gv.w;
    }

    // ===== FWHT-8192: h=1..2048 in-wave =====
#pragma unroll
    for (int q = 0; q < 16; ++q) {                               // h=1,2
      float x0=v[4*q],x1=v[4*q+1],x2=v[4*q+2],x3=v[4*q+3];
      float y0=x0+x1,y1=x0-x1,y2=x2+x3,y3=x2-x3;
      v[4*q]=y0+y2; v[4*q+2]=y0-y2; v[4*q+1]=y1+y3; v[4*q+3]=y1-y3;
    }
#pragma unroll
    for (int k = 0; k < 64; ++k) { float p = dpp_full<0xB1>(v[k]);  v[k] = fmaf(sg1, v[k], p); } // h=4
#pragma unroll
    for (int k = 0; k < 64; ++k) { float p = dpp_full<0x4E>(v[k]);  v[k] = fmaf(sg2, v[k], p); } // h=8
#pragma unroll
    for (int k = 0; k < 64; ++k) { float p = dpp_xor4(v[k]);        v[k] = fmaf(sg4, v[k], p); } // h=16
#pragma unroll
    for (int k = 0; k < 64; ++k) { float p = dpp_full<0x128>(v[k]); v[k] = fmaf(sg8, v[k], p); } // h=32
#pragma unroll
    for (int k = 0; k < 64; k += 2) bfly_pl16(v[k], v[k+1], sg16);                               // h=64
#pragma unroll
    for (int k = 0; k < 64; k += 2) bfly_pl32(v[k], v[k+1], sg32);                               // h=128
#pragma unroll
    for (int b = 1; b < 16; b <<= 1)                                                             // h=256..2048
#pragma unroll
      for (int q = 0; q < 16; ++q) if (!(q & b))
#pragma unroll
        for (int c = 0; c < 4; ++c) {
          float lo = v[4*q+c], hi = v[4*(q|b)+c];
          v[4*q+c] = lo + hi; v[4*(q|b)+c] = lo - hi;
        }

    // ===== h=4096 across the two waves via LDS half-exchange =====
    if (wave == 1) {
#pragma unroll
      for (int q = 0; q < 16; ++q) {
        int Q = (lane & 31) + (q << 5) + ((lane >> 5) << 9);
        X4s[Q] = make_float4(v[4*q], v[4*q+1], v[4*q+2], v[4*q+3]);
      }
    }
    __syncthreads();   // #2 (per row)
    if (wave == 0) {
#pragma unroll
      for (int q = 0; q < 16; ++q) {
        int Q = (lane & 31) + (q << 5) + ((lane >> 5) << 9);
        float4 h4 = X4s[Q];
        float s0 = v[4*q+0] + h4.x, d0 = v[4*q+0] - h4.x;
        float s1 = v[4*q+1] + h4.y, d1 = v[4*q+1] - h4.y;
        float s2 = v[4*q+2] + h4.z, d2 = v[4*q+2] - h4.z;
        float s3 = v[4*q+3] + h4.w, d3 = v[4*q+3] - h4.w;
        X4s[Q] = make_float4(d0, d1, d2, d3);
        v[4*q+0]=s0; v[4*q+1]=s1; v[4*q+2]=s2; v[4*q+3]=s3;
      }
    }
    __syncthreads();   // #3 (per row)
    if (wave == 1) {
#pragma unroll
      for (int q = 0; q < 16; ++q) {
        int Q = (lane & 31) + (q << 5) + ((lane >> 5) << 9);
        float4 d4 = X4s[Q];
        v[4*q+0]=d4.x; v[4*q+1]=d4.y; v[4*q+2]=d4.z; v[4*q+3]=d4.w;
      }
    }

    // ===== epilogue: cos(Vx + 2*pi*U) * sqrt(2/O) =====
    {
      float4* out4 = reinterpret_cast<float4*>(outg + (size_t)(row0 + rr) * D_OUT);
#pragma unroll
      for (int q = 0; q < 16; ++q) {
        int idx = lane + 64 * q + 1024 * wave;
        float4 s4 = S4[idx], u4 = U4[idx], res;
        float rev;
        rev = fmaf(v[4*q+0]*s4.x, c1, u4.x); rev -= rintf(rev); res.x = __builtin_amdgcn_cosf(rev) * 0.015625f;
        rev = fmaf(v[4*q+1]*s4.y, c1, u4.y); rev -= rintf(rev); res.y = __builtin_amdgcn_cosf(rev) * 0.015625f;
        rev = fmaf(v[4*q+2]*s4.z, c1, u4.z); rev -= rintf(rev); res.z = __builtin_amdgcn_cosf(rev) * 0.015625f;
        rev = fmaf(v[4*q+3]*s4.w, c1, u4.w); rev -= rintf(rev); res.w = __builtin_amdgcn_cosf(rev) * 0.015625f;
        out4[idx] = res;
      }
    }
  }
}

extern "C" void kernel_launch(void* const* d_in, const int* in_sizes, int n_in,
                              void* d_out, int out_size, void* d_ws, size_t ws_size,
                              hipStream_t stream) {
  const float* x = (const float*)d_in[0];
  const float* B = (const float*)d_in[1];
  const float* G = (const float*)d_in[2];
  const float* S = (const float*)d_in[3];
  const int*   P = (const int*)d_in[4];
  const float* U = (const float*)d_in[5];
  float* out = (float*)d_out;
  const int rows = in_sizes[0] / D_IN;  // 2048
  fastfood_kernel<<<rows / 2, 128, 0, stream>>>(x, B, G, S, P, U, out);
}

// Round 7
// 27.395 us; speedup vs baseline: 2.0634x; 2.0634x over previous
//
#include <hip/hip_runtime.h>
#include <math.h>

#define D_IN  2048
#define D_OUT 8192

// One row per 256-thread block (4 waves). No redundant work: FWHT-2048 is
// distributed (8 elems/thread), FWHT-8192 is 32 elems/thread. Cross-lane
// butterflies on the VALU pipe (DPP / permlane_swap); wave-crossing bits via
// a single 4-way LDS combine per transform (own quarter kept in registers).
// Ascending-h stage order, exact lo+hi / lo-hi association (matches the
// reference's fp32 rounding; commutative-add operand swaps only).
//
// DPP direction convention (GCN): row_ror:N => dst[i] = src[(i-N) mod 16].

#if __has_builtin(__builtin_amdgcn_permlane16_swap) && __has_builtin(__builtin_amdgcn_permlane32_swap)
#define HAVE_PLSWAP 1
#endif

template<int CTRL>
__device__ __forceinline__ float dpp_full(float x) {
  int xi = __float_as_int(x);
  return __int_as_float(__builtin_amdgcn_update_dpp(xi, xi, CTRL, 0xF, 0xF, true));
}
// partner across lane-xor-4: ror:4 feeds banks {1,3} (bit2=1), ror:12 feeds {0,2}
__device__ __forceinline__ float dpp_xor4(float x) {
  int xi = __float_as_int(x);
  int r = __builtin_amdgcn_update_dpp(0, xi, 0x124, 0xF, 0xA, false);  // ror:4  -> banks 1,3
  r     = __builtin_amdgcn_update_dpp(r,  xi, 0x12C, 0xF, 0x5, false); // ror:12 -> banks 0,2
  return __int_as_float(r);
}
__device__ __forceinline__ void bfly_pl16(float& A, float& B, float sgn) {
#ifdef HAVE_PLSWAP
  auto r0 = __builtin_amdgcn_permlane16_swap(__float_as_uint(A), __float_as_uint(B), false, false);
  float lo = __uint_as_float(r0[0]), hi = __uint_as_float(r0[1]);
  float s = lo + hi, d = lo - hi;
  auto r1 = __builtin_amdgcn_permlane16_swap(__float_as_uint(s), __float_as_uint(d), false, false);
  A = __uint_as_float(r1[0]); B = __uint_as_float(r1[1]);
  (void)sgn;
#else
  float pA = __shfl_xor(A, 16, 64); A = fmaf(sgn, A, pA);
  float pB = __shfl_xor(B, 16, 64); B = fmaf(sgn, B, pB);
#endif
}
__device__ __forceinline__ void bfly_pl32(float& A, float& B, float sgn) {
#ifdef HAVE_PLSWAP
  auto r0 = __builtin_amdgcn_permlane32_swap(__float_as_uint(A), __float_as_uint(B), false, false);
  float lo = __uint_as_float(r0[0]), hi = __uint_as_float(r0[1]);
  float s = lo + hi, d = lo - hi;
  auto r1 = __builtin_amdgcn_permlane32_swap(__float_as_uint(s), __float_as_uint(d), false, false);
  A = __uint_as_float(r1[0]); B = __uint_as_float(r1[1]);
  (void)sgn;
#else
  float pA = __shfl_xor(A, 32, 64); A = fmaf(sgn, A, pA);
  float pB = __shfl_xor(B, 32, 64); B = fmaf(sgn, B, pB);
#endif
}

__global__ __launch_bounds__(256) void fastfood_kernel(
    const float* __restrict__ xg, const float* __restrict__ Bg,
    const float* __restrict__ Gg, const float* __restrict__ Sg,
    const int*   __restrict__ Pg, const float* __restrict__ Ug,
    float* __restrict__ outg)
{
  __shared__ float4 A4s[D_IN / 4];    // 8 KB: FWHT-2048 result (linear in element index)
  __shared__ float4 X4s[D_OUT / 4];   // 32 KB: 4-way exchange buffer (first 8 KB reused for FWHT-2048)

  const int t = threadIdx.x, lane = t & 63, wave = t >> 6;
  const int row = blockIdx.x;
  const float sg1  = (lane & 1)  ? -1.f : 1.f;
  const float sg2  = (lane & 2)  ? -1.f : 1.f;
  const float sg4  = (lane & 4)  ? -1.f : 1.f;
  const float sg8  = (lane & 8)  ? -1.f : 1.f;
  const float sg16 = (lane & 16) ? -1.f : 1.f;
  const float sg32 = (lane & 32) ? -1.f : 1.f;
  // 4-way combine signs (pairing under h and 2h, derived & parity-checked):
  //   u_m = fmaf(s0, own, pB); u_o = fmaf(s0, pC, pD); res = fmaf(s1, u_m, u_o)
  const float s0w = (wave & 1) ? -1.f : 1.f;
  const float s1w = (wave & 2) ? -1.f : 1.f;

  // ===== FWHT-2048 of B*x, distributed: d = c | lane<<2 | m<<8 | wave<<9 =====
  float a[8];   // a[4m+c]
  {
    const float4* x4 = reinterpret_cast<const float4*>(xg + (size_t)row * D_IN);
    const float4* B4 = reinterpret_cast<const float4*>(Bg);
#pragma unroll
    for (int m = 0; m < 2; ++m) {
      int f = lane + 64 * m + 128 * wave;
      float4 xv = x4[f], bv = B4[f];
      a[4*m+0] = xv.x * bv.x; a[4*m+1] = xv.y * bv.y;
      a[4*m+2] = xv.z * bv.z; a[4*m+3] = xv.w * bv.w;
    }
  }
#pragma unroll
  for (int m = 0; m < 2; ++m) {                                   // h=1,2
    float x0=a[4*m],x1=a[4*m+1],x2=a[4*m+2],x3=a[4*m+3];
    float y0=x0+x1,y1=x0-x1,y2=x2+x3,y3=x2-x3;
    a[4*m]=y0+y2; a[4*m+2]=y0-y2; a[4*m+1]=y1+y3; a[4*m+3]=y1-y3;
  }
#pragma unroll
  for (int k = 0; k < 8; ++k) { float p = dpp_full<0xB1>(a[k]);  a[k] = fmaf(sg1, a[k], p); }   // h=4
#pragma unroll
  for (int k = 0; k < 8; ++k) { float p = dpp_full<0x4E>(a[k]);  a[k] = fmaf(sg2, a[k], p); }   // h=8
#pragma unroll
  for (int k = 0; k < 8; ++k) { float p = dpp_xor4(a[k]);        a[k] = fmaf(sg4, a[k], p); }   // h=16
#pragma unroll
  for (int k = 0; k < 8; ++k) { float p = dpp_full<0x128>(a[k]); a[k] = fmaf(sg8, a[k], p); }   // h=32
#pragma unroll
  for (int k = 0; k < 8; k += 2) bfly_pl16(a[k], a[k+1], sg16);                                 // h=64
#pragma unroll
  for (int k = 0; k < 8; k += 2) bfly_pl32(a[k], a[k+1], sg32);                                 // h=128
#pragma unroll
  for (int c = 0; c < 4; ++c) {                                   // h=256 (m bit)
    float lo = a[c], hi = a[4+c];
    a[c] = lo + hi; a[4+c] = lo - hi;
  }
  // h=512,1024: 4-way cross-wave combine via first 8 KB of X
#pragma unroll
  for (int m = 0; m < 2; ++m)
    X4s[lane + 64 * m + 128 * wave] = make_float4(a[4*m], a[4*m+1], a[4*m+2], a[4*m+3]);
  __syncthreads();   // #1
#pragma unroll
  for (int m = 0; m < 2; ++m) {
    int fb = lane + 64 * m;
    float4 B4v = X4s[fb + 128 * (wave ^ 1)];
    float4 C4v = X4s[fb + 128 * (wave ^ 2)];
    float4 D4v = X4s[fb + 128 * (wave ^ 3)];
    float pB[4] = {B4v.x, B4v.y, B4v.z, B4v.w};
    float pC[4] = {C4v.x, C4v.y, C4v.z, C4v.w};
    float pD[4] = {D4v.x, D4v.y, D4v.z, D4v.w};
#pragma unroll
    for (int c = 0; c < 4; ++c) {
      float um = fmaf(s0w, a[4*m+c], pB[c]);
      float uo = fmaf(s0w, pC[c], pD[c]);
      a[4*m+c] = fmaf(s1w, um, uo);
    }
  }
  // store final FWHT-2048 (linear: A4s[d>>2], d = c|lane<<2|m<<8|wave<<9)
#pragma unroll
  for (int m = 0; m < 2; ++m)
    A4s[lane + 64 * m + 128 * wave] = make_float4(a[4*m], a[4*m+1], a[4*m+2], a[4*m+3]);
  __syncthreads();   // #2 (A ready; X1 reads done -> X reusable)

  // ===== gather + Gaussian scale: o = c | lane<<2 | q<<8 | wave<<11 =====
  float v[32];
  {
    const float* a_f = reinterpret_cast<const float*>(A4s);
    const int4*   P4 = reinterpret_cast<const int4*>(Pg);
    const float4* G4 = reinterpret_cast<const float4*>(Gg);
#pragma unroll
    for (int q = 0; q < 8; ++q) {
      int idx = lane + 64 * q + 512 * wave;
      int4 pp = P4[idx]; float4 gv = G4[idx];
      v[4*q+0] = a_f[pp.x & (D_IN-1)] * gv.x;
      v[4*q+1] = a_f[pp.y & (D_IN-1)] * gv.y;
      v[4*q+2] = a_f[pp.z & (D_IN-1)] * gv.z;
      v[4*q+3] = a_f[pp.w & (D_IN-1)] * gv.w;
    }
  }

  // ===== FWHT-8192: h=1,2 (reg), h=4..128 (lane), h=256..1024 (q) =====
#pragma unroll
  for (int q = 0; q < 8; ++q) {
    float x0=v[4*q],x1=v[4*q+1],x2=v[4*q+2],x3=v[4*q+3];
    float y0=x0+x1,y1=x0-x1,y2=x2+x3,y3=x2-x3;
    v[4*q]=y0+y2; v[4*q+2]=y0-y2; v[4*q+1]=y1+y3; v[4*q+3]=y1-y3;
  }
#pragma unroll
  for (int k = 0; k < 32; ++k) { float p = dpp_full<0xB1>(v[k]);  v[k] = fmaf(sg1, v[k], p); }  // h=4
#pragma unroll
  for (int k = 0; k < 32; ++k) { float p = dpp_full<0x4E>(v[k]);  v[k] = fmaf(sg2, v[k], p); }  // h=8
#pragma unroll
  for (int k = 0; k < 32; ++k) { float p = dpp_xor4(v[k]);        v[k] = fmaf(sg4, v[k], p); }  // h=16
#pragma unroll
  for (int k = 0; k < 32; ++k) { float p = dpp_full<0x128>(v[k]); v[k] = fmaf(sg8, v[k], p); }  // h=32
#pragma unroll
  for (int k = 0; k < 32; k += 2) bfly_pl16(v[k], v[k+1], sg16);                                // h=64
#pragma unroll
  for (int k = 0; k < 32; k += 2) bfly_pl32(v[k], v[k+1], sg32);                                // h=128
#pragma unroll
  for (int b = 1; b < 8; b <<= 1)                                                               // h=256,512,1024
#pragma unroll
    for (int q = 0; q < 8; ++q) if (!(q & b))
#pragma unroll
      for (int c = 0; c < 4; ++c) {
        float lo = v[4*q+c], hi = v[4*(q|b)+c];
        v[4*q+c] = lo + hi; v[4*(q|b)+c] = lo - hi;
      }

  // ===== h=2048,4096: 4-way cross-wave combine via X (32 KB) =====
#pragma unroll
  for (int q = 0; q < 8; ++q)
    X4s[lane + 64 * q + 512 * wave] = make_float4(v[4*q], v[4*q+1], v[4*q+2], v[4*q+3]);
  __syncthreads();   // #3
#pragma unroll
  for (int q = 0; q < 8; ++q) {
    int fb = lane + 64 * q;
    float4 B4v = X4s[fb + 512 * (wave ^ 1)];
    float4 C4v = X4s[fb + 512 * (wave ^ 2)];
    float4 D4v = X4s[fb + 512 * (wave ^ 3)];
    float pB[4] = {B4v.x, B4v.y, B4v.z, B4v.w};
    float pC[4] = {C4v.x, C4v.y, C4v.z, C4v.w};
    float pD[4] = {D4v.x, D4v.y, D4v.z, D4v.w};
#pragma unroll
    for (int c = 0; c < 4; ++c) {
      float um = fmaf(s0w, v[4*q+c], pB[c]);
      float uo = fmaf(s0w, pC[c], pD[c]);
      v[4*q+c] = fmaf(s1w, um, uo);
    }
  }

  // ===== epilogue: cos(Vx + 2*pi*U) * sqrt(2/O) =====
  {
    const float c1 = (float)(1.0 / (6.283185307179586 * 90.50966799187808)); // 1/(2*pi*sqrt(8192))
    const float4* S4 = reinterpret_cast<const float4*>(Sg);
    const float4* U4 = reinterpret_cast<const float4*>(Ug);
    float4* out4 = reinterpret_cast<float4*>(outg + (size_t)row * D_OUT);
#pragma unroll
    for (int q = 0; q < 8; ++q) {
      int idx = lane + 64 * q + 512 * wave;
      float4 s4 = S4[idx], u4 = U4[idx], res;
      float rev;
      rev = fmaf(v[4*q+0]*s4.x, c1, u4.x); rev -= rintf(rev); res.x = __builtin_amdgcn_cosf(rev) * 0.015625f;
      rev = fmaf(v[4*q+1]*s4.y, c1, u4.y); rev -= rintf(rev); res.y = __builtin_amdgcn_cosf(rev) * 0.015625f;
      rev = fmaf(v[4*q+2]*s4.z, c1, u4.z); rev -= rintf(rev); res.z = __builtin_amdgcn_cosf(rev) * 0.015625f;
      rev = fmaf(v[4*q+3]*s4.w, c1, u4.w); rev -= rintf(rev); res.w = __builtin_amdgcn_cosf(rev) * 0.015625f;
      out4[idx] = res;
    }
  }
}

extern "C" void kernel_launch(void* const* d_in, const int* in_sizes, int n_in,
                              void* d_out, int out_size, void* d_ws, size_t ws_size,
                              hipStream_t stream) {
  const float* x = (const float*)d_in[0];
  const float* B = (const float*)d_in[1];
  const float* G = (const float*)d_in[2];
  const float* S = (const float*)d_in[3];
  const int*   P = (const int*)d_in[4];
  const float* U = (const float*)d_in[5];
  float* out = (float*)d_out;
  const int rows = in_sizes[0] / D_IN;  // 2048
  fastfood_kernel<<<rows, 256, 0, stream>>>(x, B, G, S, P, U, out);
}